// Round 5
// baseline (15386.580 us; speedup 1.0000x reference)
//
#include <hip/hip_runtime.h>
#include <hip/hip_bf16.h>
#include <hip/hip_fp16.h>

typedef unsigned int uint32;
typedef _Float16 hf2 __attribute__((ext_vector_type(2)));

#define NT 1024

// ---------- helpers ----------
__device__ __forceinline__ float bfu(unsigned short v) { return __uint_as_float(((uint32)v) << 16); }
__device__ __forceinline__ unsigned short f2bf(float f) {
    uint32 u = __float_as_uint(f);
    u = (u + 0x7fffu + ((u >> 16) & 1u)) >> 16;
    return (unsigned short)u;
}
__device__ __forceinline__ uint32 pack_f16(float a, float b) {
    __half ha = __float2half_rn(a), hb = __float2half_rn(b);
    return (uint32)__half_as_ushort(ha) | ((uint32)__half_as_ushort(hb) << 16);
}
__device__ __forceinline__ unsigned short f16u(float a) {
    return __half_as_ushort(__float2half_rn(a));
}
__device__ __forceinline__ float fast_tanh(float x) {
    x = fminf(fmaxf(x, -15.f), 15.f);
    float e = __expf(2.f * x);
    return __fdividef(e - 1.f, e + 1.f);
}
__device__ __forceinline__ float fast_sigmoid(float x) {
    return __fdividef(1.f, 1.f + __expf(-x));
}
__device__ __forceinline__ float fdot2(uint32 w, uint32 v, float acc) {
#if __has_builtin(__builtin_amdgcn_fdot2)
    return __builtin_amdgcn_fdot2(__builtin_bit_cast(hf2, w), __builtin_bit_cast(hf2, v), acc, false);
#else
    __half2 wh = __builtin_bit_cast(__half2, w), vh = __builtin_bit_cast(__half2, v);
    float2 wf = __half22float2(wh), vf = __half22float2(vh);
    return fmaf(wf.y, vf.y, fmaf(wf.x, vf.x, acc));
#endif
}

// wave-wide: wait until all 8 flags f[0..8) >= tgt (lanes replicate mod 8).
__device__ __forceinline__ void acq8(const uint32* f, uint32 tgt, int lane) {
    int guard = 0;
    for (;;) {
        uint32 v = __hip_atomic_load(f + (lane & 7), __ATOMIC_ACQUIRE, __HIP_MEMORY_SCOPE_AGENT);
        if (__all(v >= tgt)) break;
        __builtin_amdgcn_s_sleep(1);
        if (++guard > (1 << 16)) break;  // safety valve: wrong beats hang
    }
}
__device__ __forceinline__ void rel(uint32* p, uint32 v) {
    __hip_atomic_store(p, v, __ATOMIC_RELEASE, __HIP_MEMORY_SCOPE_AGENT);
}

// ---------- prep 1: f16 weights, two layouts ----------
// We2r: uint32[32768], idx=(ch*128+s)*32+i -> pack(We[s][ch*64+2i], We[s][ch*64+2i+1])
//   (attention thread tid=ch*128+s preloads 32 consecutive uint32 into regs)
// Wg: uint32[8][128][192], [jg][g][np]: g -> type=g>>5, j=g&31, gg=type*256+jg*32+j
//   np -> v-K pair k0=2np of [xw(128)|h(256)]:
//   k0<128: (W_ih[gg][k0],W_ih[gg][k0+1]) else jj=k0-128: (W_hh[gg][jj],W_hh[gg][jj+1])
__global__ void prep_weights(const float* __restrict__ We, const float* __restrict__ W_ih,
                             const float* __restrict__ W_hh, uint32* __restrict__ We2r,
                             uint32* __restrict__ Wg) {
    int idx = blockIdx.x * 256 + threadIdx.x;
    if (idx < 32768) {
        int i = idx & 31, s = (idx >> 5) & 127, ch = idx >> 12;
        int j0 = ch * 64 + 2 * i;
        We2r[idx] = pack_f16(We[s * 512 + j0], We[s * 512 + j0 + 1]);
    } else if (idx < 229376) {
        int i2 = idx - 32768;
        int np = i2 % 192;
        int g = (i2 / 192) & 127;
        int jg = i2 / (192 * 128);
        int type = g >> 5, j = g & 31;
        int gg = type * 256 + jg * 32 + j;
        int k0 = 2 * np;
        float w0, w1;
        if (k0 < 128) {
            w0 = W_ih[gg * 128 + k0];
            w1 = W_ih[gg * 128 + k0 + 1];
        } else {
            int jj = k0 - 128;
            w0 = W_hh[gg * 256 + jj];
            w1 = W_hh[gg * 256 + jj + 1];
        }
        Wg[i2] = pack_f16(w0, w1);
    }
}

// ---------- prep 2: Ux[b,s,n] = sum_t x[b,t,n] * Ue[s,t]  (bf16 out) ----------
__global__ void ux_kernel(const float* __restrict__ x, const float* __restrict__ Ue,
                          unsigned short* __restrict__ Uxg) {
    int b = blockIdx.x >> 1, h = blockIdx.x & 1;
    int n = threadIdx.x & 127, sg = threadIdx.x >> 7;
    int s0 = h * 64 + sg * 16;
    float acc[16];
#pragma unroll
    for (int k = 0; k < 16; ++k) acc[k] = 0.f;
    for (int t0 = 0; t0 < 128; t0 += 16) {
        float xv[16];
#pragma unroll
        for (int tt = 0; tt < 16; ++tt) xv[tt] = x[(b * 128 + t0 + tt) * 128 + n];
#pragma unroll
        for (int k = 0; k < 16; ++k) {
            const float4* uep = (const float4*)(Ue + (s0 + k) * 128 + t0);
            float4 u0 = uep[0], u1 = uep[1], u2 = uep[2], u3 = uep[3];
            acc[k] += xv[0] * u0.x + xv[1] * u0.y + xv[2] * u0.z + xv[3] * u0.w
                    + xv[4] * u1.x + xv[5] * u1.y + xv[6] * u1.z + xv[7] * u1.w
                    + xv[8] * u2.x + xv[9] * u2.y + xv[10] * u2.z + xv[11] * u2.w
                    + xv[12] * u3.x + xv[13] * u3.y + xv[14] * u3.z + xv[15] * u3.w;
        }
    }
#pragma unroll
    for (int k = 0; k < 16; ++k)
        Uxg[b * 16384 + (s0 + k) * 128 + n] = f2bf(acc[k]);
}

// ---------- main: 256 blocks. 0..127 = attention (per batch), 128..255 = gate
// (jg = k&7 of 8 j-slices, bg = k>>3 of 16 batch groups). Weight-stationary:
// attention holds We in VGPRs; gate holds its 96 KB W-slice in LDS. Per-step
// cross-CU traffic: f16 boards (h/c/xw), ping-pong slots, release/acquire
// agent atomics only (no threadfence). LDS 112 KB/block -> 1 block/CU ->
// all 256 co-resident. ----------
#define LDS_BYTES 112256
__global__ __launch_bounds__(NT)
void encoder_kernel(const float* __restrict__ x, const float* __restrict__ v_e,
                    const float* __restrict__ b_ih, const float* __restrict__ b_hh,
                    const unsigned short* __restrict__ Uxg, const uint32* __restrict__ We2r,
                    const uint32* __restrict__ Wg, unsigned short* __restrict__ h_board,
                    unsigned short* __restrict__ c_board, uint32* __restrict__ xw_board,
                    uint32* __restrict__ a_flag, uint32* __restrict__ g_flag,
                    float* __restrict__ out) {
    __shared__ __align__(16) char smem[LDS_BYTES];
    const int tid = threadIdx.x;
    const int bid = blockIdx.x;
    const int lane = tid & 63;

    if (bid < 128) {
        // ================= ATTENTION CU (batch b) =================
        const int b = bid;
        unsigned short* Ux_s = (unsigned short*)smem;          // 32 KB
        uint32* hs_l = (uint32*)(smem + 32768);                // 1 KB
        float* part1 = (float*)(smem + 33792);                 // 4 KB [ch][s]
        float* part2 = (float*)(smem + 37888);                 // 4 KB [ch][n]
        float* web_s = (float*)(smem + 41984);                 // 512 B
        float* ve_s  = (float*)(smem + 42496);                 // 512 B

        {   // stage Ux tile
            const uint4* src = (const uint4*)(Uxg + b * 16384);
            uint4* dst = (uint4*)Ux_s;
            dst[tid] = src[tid];
            dst[tid + 1024] = src[tid + 1024];
        }
        if (tid < 128) ve_s[tid] = v_e[tid];
        // preload We fragment into regs: 32 uint32 (64 f16)
        uint4 wer[8];
        {
            const uint4* wesrc = ((const uint4*)We2r) + tid * 8;
#pragma unroll
            for (int q = 0; q < 8; ++q) wer[q] = wesrc[q];
        }
        __syncthreads();

        const int s = tid & 127, ch = tid >> 7;
        const uint32* gf = g_flag + (b >> 3) * 8;

        for (int t = 0; t < 128; ++t) {
            float2 xv = make_float2(0.f, 0.f);
            if (tid < 64) xv = *(const float2*)(x + (b * 128 + t) * 128 + 2 * lane);
            // wait h(t),c(t) then stage hs pairs (stagers only)
            if (tid < 256) {
                if (t) acq8(gf, (uint32)t, lane);
                const uint32* hb32 = (const uint32*)(h_board + (t & 1) * 32768);
                const uint32* cb32 = (const uint32*)(c_board + (t & 1) * 32768);
                hs_l[tid] = (tid < 128) ? hb32[b * 128 + tid] : cb32[b * 128 + (tid - 128)];
            }
            __syncthreads();  // A1
            // ph1: web partial, thread (s, ch): 64 j's via regs
            {
                const uint32* hsc = hs_l + ch * 32;
                float a0 = 0.f, a1 = 0.f;
#pragma unroll
                for (int q = 0; q < 8; ++q) {
                    uint4 w = wer[q];
                    a0 = fdot2(w.x, hsc[4 * q + 0], a0);
                    a1 = fdot2(w.y, hsc[4 * q + 1], a1);
                    a0 = fdot2(w.z, hsc[4 * q + 2], a0);
                    a1 = fdot2(w.w, hsc[4 * q + 3], a1);
                }
                part1[ch * 128 + s] = a0 + a1;
            }
            __syncthreads();  // A2
            if (tid < 128) {
                float w = 0.f;
#pragma unroll
                for (int g = 0; g < 8; ++g) w += part1[g * 128 + tid];
                web_s[tid] = w;
            }
            __syncthreads();  // A3
            // ph2: scores partial, thread (n=s, chunk ch of 16 s)
            {
                float acc = 0.f;
#pragma unroll 4
                for (int kk = 0; kk < 16; ++kk) {
                    int ss = ch * 16 + kk;
                    acc += ve_s[ss] * fast_tanh(web_s[ss] + bfu(Ux_s[ss * 128 + s]));
                }
                part2[ch * 128 + s] = acc;
            }
            __syncthreads();  // A4
            // ph3: softmax + xw publish (wave 0)
            if (tid < 64) {
                float v0 = 0.f, v1 = 0.f;
#pragma unroll
                for (int g = 0; g < 8; ++g) {
                    v0 += part2[g * 128 + 2 * lane];
                    v1 += part2[g * 128 + 2 * lane + 1];
                }
                float m = fmaxf(v0, v1);
#pragma unroll
                for (int off = 32; off > 0; off >>= 1) m = fmaxf(m, __shfl_xor(m, off));
                float e0 = __expf(v0 - m), e1 = __expf(v1 - m);
                float ssum = e0 + e1;
#pragma unroll
                for (int off = 32; off > 0; off >>= 1) ssum += __shfl_xor(ssum, off);
                float inv = __fdividef(1.f, ssum);
                xw_board[(t & 1) * 8192 + b * 64 + lane] = pack_f16(xv.x * e0 * inv, xv.y * e1 * inv);
                if (lane == 0) rel(&a_flag[b], (uint32)(t + 1));
            }
        }
    } else {
        // ================= GATE CU (jg, bg) =================
        const int k = bid - 128;
        const int jg = k & 7, bg = k >> 3;
        uint32* W_l = (uint32*)smem;                     // 128 rows x 196 (pad)
        uint32* v_l = (uint32*)(smem + 100352);          // 8 rows x 196
        float* gates_s = (float*)(smem + 106624);        // [g][b] = [tid]
        float* c_s = (float*)(smem + 110720);            // [j*8+b], 256 f32
        float* bias_s = (float*)(smem + 111744);         // [g_local]

        {   // stage weight slice 96 KB -> LDS (padded rows)
            const uint4* src = ((const uint4*)Wg) + jg * 6144;
#pragma unroll
            for (int r = 0; r < 6; ++r) {
                int q = tid + r * NT;
                int g = q / 48, c4 = q % 48;
                *(uint4*)(W_l + g * 196 + c4 * 4) = src[q];
            }
        }
        if (tid < 128) {
            int type = tid >> 5, j = tid & 31;
            int gg = type * 256 + jg * 32 + j;
            bias_s[tid] = b_ih[gg] + b_hh[gg];
        }
        if (tid < 256) c_s[tid] = 0.f;
        __syncthreads();

        const int g = tid >> 3, bl = tid & 7;
        const uint32* wrow = W_l + g * 196;
        const uint32* vrow = v_l + bl * 196;
        const uint32* gfl = g_flag + bg * 8;
        const uint32* afl = a_flag + bg * 8;

        for (int t = 0; t < 128; ++t) {
            // wait h(t) (all threads stage), stage h pairs into v_l
            if (t) acq8(gfl, (uint32)t, lane);
            {
                const uint32* hb32 = (const uint32*)(h_board + (t & 1) * 32768);
                int b = tid >> 7, i = tid & 127;
                v_l[b * 196 + 64 + i] = hb32[(bg * 8 + b) * 128 + i];
            }
            __syncthreads();  // B1
            // h-part GEMM: np pairs [64,192) = c4 [16,48)
            float acc0 = bias_s[g], acc1 = 0.f;
#pragma unroll 8
            for (int c4 = 16; c4 < 48; ++c4) {
                uint4 w = *(const uint4*)(wrow + c4 * 4);
                uint4 v = *(const uint4*)(vrow + c4 * 4);
                acc0 = fdot2(w.x, v.x, acc0);
                acc1 = fdot2(w.y, v.y, acc1);
                acc0 = fdot2(w.z, v.z, acc0);
                acc1 = fdot2(w.w, v.w, acc1);
            }
            // wait xw(t), stage
            if (tid < 512) {
                acq8(afl, (uint32)(t + 1), lane);
                int b = tid >> 6, i = tid & 63;
                v_l[b * 196 + i] = xw_board[(t & 1) * 8192 + (bg * 8 + b) * 64 + i];
            }
            __syncthreads();  // B2
            // xw-part GEMM: c4 [0,16)
#pragma unroll 8
            for (int c4 = 0; c4 < 16; ++c4) {
                uint4 w = *(const uint4*)(wrow + c4 * 4);
                uint4 v = *(const uint4*)(vrow + c4 * 4);
                acc0 = fdot2(w.x, v.x, acc0);
                acc1 = fdot2(w.y, v.y, acc1);
                acc0 = fdot2(w.z, v.z, acc0);
                acc1 = fdot2(w.w, v.w, acc1);
            }
            gates_s[tid] = acc0 + acc1;
            __syncthreads();  // B3
            // pointwise + publish (wave 0 only: 4 units per lane)
            if (tid < 64) {
#pragma unroll
                for (int r = 0; r < 4; ++r) {
                    int u = lane + 64 * r;
                    int j = u >> 3, b = u & 7;
                    float gi = gates_s[(j) * 8 + b];
                    float gf2 = gates_s[(32 + j) * 8 + b];
                    float gG = gates_s[(64 + j) * 8 + b];
                    float go = gates_s[(96 + j) * 8 + b];
                    float c = c_s[u];
                    float c2 = fast_sigmoid(gf2) * c + fast_sigmoid(gi) * fast_tanh(gG);
                    float h2 = fast_sigmoid(go) * fast_tanh(c2);
                    c_s[u] = c2;
                    int bglob = bg * 8 + b, jglob = jg * 32 + j;
                    out[(t * 128 + bglob) * 256 + jglob] = h2;
                    if (t < 127) {
                        h_board[((t + 1) & 1) * 32768 + bglob * 256 + jglob] = f16u(h2);
                        c_board[((t + 1) & 1) * 32768 + bglob * 256 + jglob] = f16u(c2);
                    }
                }
                if (t < 127 && lane == 0) rel(&g_flag[bg * 8 + jg], (uint32)(t + 1));
            }
        }
    }
}

extern "C" void kernel_launch(void* const* d_in, const int* in_sizes, int n_in,
                              void* d_out, int out_size, void* d_ws, size_t ws_size,
                              hipStream_t stream) {
    const float* x    = (const float*)d_in[0];
    const float* We   = (const float*)d_in[1];
    const float* Ue   = (const float*)d_in[2];
    const float* v_e  = (const float*)d_in[3];
    const float* W_ih = (const float*)d_in[4];
    const float* W_hh = (const float*)d_in[5];
    const float* b_ih = (const float*)d_in[6];
    const float* b_hh = (const float*)d_in[7];
    float* out = (float*)d_out;

    char* w = (char*)d_ws;
    unsigned short* Uxg = (unsigned short*)w;               // 4 MB
    uint32* We2r = (uint32*)(w + 4194304);                  // 128 KB
    uint32* Wg   = (uint32*)(w + 4325376);                  // 768 KB
    unsigned short* h_board = (unsigned short*)(w + 5111808); // 128 KB
    unsigned short* c_board = (unsigned short*)(w + 5242880); // 128 KB
    uint32* xw_board = (uint32*)(w + 5373952);              // 64 KB
    uint32* a_flag = (uint32*)(w + 5439488);                // 512 B
    uint32* g_flag = (uint32*)(w + 5440000);                // 512 B

    // zero boards (h/c slot0 = h0/c0 = 0) + flags, every launch
    hipMemsetAsync(w + 5111808, 0, 328704, stream);
    prep_weights<<<896, 256, 0, stream>>>(We, W_ih, W_hh, We2r, Wg);
    ux_kernel<<<256, 512, 0, stream>>>(x, Ue, Uxg);
    encoder_kernel<<<256, NT, 0, stream>>>(x, v_e, b_ih, b_hh, Uxg, We2r, Wg,
                                           h_board, c_board, xw_board,
                                           a_flag, g_flag, out);
}

// Round 6
// 2339.952 us; speedup vs baseline: 6.5756x; 6.5756x over previous
//
#include <hip/hip_runtime.h>
#include <hip/hip_bf16.h>
#include <hip/hip_fp16.h>

typedef unsigned int uint32;
typedef _Float16 hf2 __attribute__((ext_vector_type(2)));

#define NT 1024

// ---------- helpers ----------
__device__ __forceinline__ float bfu(unsigned short v) { return __uint_as_float(((uint32)v) << 16); }
__device__ __forceinline__ unsigned short f2bf(float f) {
    uint32 u = __float_as_uint(f);
    u = (u + 0x7fffu + ((u >> 16) & 1u)) >> 16;
    return (unsigned short)u;
}
__device__ __forceinline__ uint32 pack_f16(float a, float b) {
    __half ha = __float2half_rn(a), hb = __float2half_rn(b);
    return (uint32)__half_as_ushort(ha) | ((uint32)__half_as_ushort(hb) << 16);
}
__device__ __forceinline__ float fast_tanh(float x) {
    x = fminf(fmaxf(x, -15.f), 15.f);
    float e = __expf(2.f * x);
    return __fdividef(e - 1.f, e + 1.f);
}
__device__ __forceinline__ float fast_sigmoid(float x) {
    return __fdividef(1.f, 1.f + __expf(-x));
}
__device__ __forceinline__ float fdot2(uint32 w, uint32 v, float acc) {
#if __has_builtin(__builtin_amdgcn_fdot2)
    return __builtin_amdgcn_fdot2(__builtin_bit_cast(hf2, w), __builtin_bit_cast(hf2, v), acc, false);
#else
    __half2 wh = __builtin_bit_cast(__half2, w), vh = __builtin_bit_cast(__half2, v);
    float2 wf = __half22float2(wh), vf = __half22float2(vh);
    return fmaf(wf.y, vf.y, fmaf(wf.x, vf.x, acc));
#endif
}

// ---------- prep 1: f16 weight packs, 4 regions ----------
// Gate GEMV K-order: v = [xw(128) | h(256)], pair np covers elems (2np, 2np+1).
//   WrA[q*1024+gg],  q  0..63 : np=q      -> W_ih cols (2q, 2q+1)         (reg-resident)
//   WlB[np*1024+gg], np 0..27 : np+64     -> W_hh cols (2np, 2np+1)       (LDS-resident)
//   WsC[np*1024+gg], np 0..99 : np+92     -> W_hh cols (56+2np, 57+2np)   (streamed)
// Attention: WeT[q*1024 + ch*128 + s] = (We[s][ch*64+2q], We[s][ch*64+2q+1]), q 0..31
__global__ void prep_weights(const float* __restrict__ We, const float* __restrict__ W_ih,
                             const float* __restrict__ W_hh, uint32* __restrict__ WrA,
                             uint32* __restrict__ WlB, uint32* __restrict__ WsC,
                             uint32* __restrict__ WeT) {
    int idx = blockIdx.x * 256 + threadIdx.x;
    if (idx < 65536) {
        int gg = idx & 1023, q = idx >> 10;
        WrA[idx] = pack_f16(W_ih[gg * 128 + 2 * q], W_ih[gg * 128 + 2 * q + 1]);
    } else if (idx < 94208) {
        int i2 = idx - 65536;
        int gg = i2 & 1023, np = i2 >> 10;
        WlB[i2] = pack_f16(W_hh[gg * 256 + 2 * np], W_hh[gg * 256 + 2 * np + 1]);
    } else if (idx < 196608) {
        int i2 = idx - 94208;
        int gg = i2 & 1023, np = i2 >> 10;
        WsC[i2] = pack_f16(W_hh[gg * 256 + 56 + 2 * np], W_hh[gg * 256 + 57 + 2 * np]);
    } else if (idx < 229376) {
        int i2 = idx - 196608;
        int s = i2 & 127, ch = (i2 >> 7) & 7, q = i2 >> 10;
        int j0 = ch * 64 + 2 * q;
        WeT[i2] = pack_f16(We[s * 512 + j0], We[s * 512 + j0 + 1]);
    }
}

// ---------- prep 2: Ux[b,s,n] = sum_t x[b,t,n] * Ue[s,t]  (bf16 out) ----------
__global__ void ux_kernel(const float* __restrict__ x, const float* __restrict__ Ue,
                          unsigned short* __restrict__ Uxg) {
    int b = blockIdx.x >> 1, h = blockIdx.x & 1;
    int n = threadIdx.x & 127, sg = threadIdx.x >> 7;
    int s0 = h * 64 + sg * 16;
    float acc[16];
#pragma unroll
    for (int k = 0; k < 16; ++k) acc[k] = 0.f;
    for (int t0 = 0; t0 < 128; t0 += 16) {
        float xv[16];
#pragma unroll
        for (int tt = 0; tt < 16; ++tt) xv[tt] = x[(b * 128 + t0 + tt) * 128 + n];
#pragma unroll
        for (int k = 0; k < 16; ++k) {
            const float4* uep = (const float4*)(Ue + (s0 + k) * 128 + t0);
            float4 u0 = uep[0], u1 = uep[1], u2 = uep[2], u3 = uep[3];
            acc[k] += xv[0] * u0.x + xv[1] * u0.y + xv[2] * u0.z + xv[3] * u0.w
                    + xv[4] * u1.x + xv[5] * u1.y + xv[6] * u1.z + xv[7] * u1.w
                    + xv[8] * u2.x + xv[9] * u2.y + xv[10] * u2.z + xv[11] * u2.w
                    + xv[12] * u3.x + xv[13] * u3.y + xv[14] * u3.z + xv[15] * u3.w;
        }
    }
#pragma unroll
    for (int k = 0; k < 16; ++k)
        Uxg[b * 16384 + (s0 + k) * 128 + n] = f2bf(acc[k]);
}

// ---------- main: 128 blocks x 1024 thr, one gate per thread, partial
// weight-residency (64 pairs regs + 28 pairs LDS per gate), stream the rest.
// All sync is intra-block __syncthreads. ----------
__global__ __launch_bounds__(NT)
void encoder_kernel(const float* __restrict__ x, const float* __restrict__ v_e,
                    const float* __restrict__ b_ih, const float* __restrict__ b_hh,
                    const unsigned short* __restrict__ Uxg, const uint32* __restrict__ WrA,
                    const uint32* __restrict__ WlB, const uint32* __restrict__ WsC,
                    const uint32* __restrict__ WeT, float* __restrict__ out) {
    __shared__ __align__(16) unsigned short Ux_s[16384];  // 32 KB [s][n] bf16
    __shared__ uint32 W_l[29696];   // 116 KB: gate g's 28 LDS pairs at [g*29 .. g*29+27]
    __shared__ uint32 vh_s[192];    // v pairs: [xw(0..64) | h(64..192)]
    __shared__ uint32 hsh_s[256];   // hs pairs: [h(0..128) | c(128..256)]
    __shared__ float scr[1024];     // shared scratch: part1 / part2 / gates (disjoint lifetimes)
    __shared__ float web_s[128];
    __shared__ float ve_s[128];

    const int tid = threadIdx.x;
    const int b = blockIdx.x;
    const int lane7 = tid & 127;    // s (ph1) / n (ph2)
    const int ch = tid >> 7;        // 8-way chunk

    {   // stage Ux tile (coalesced)
        const uint4* src = (const uint4*)(Uxg + b * 16384);
        uint4* dst = (uint4*)Ux_s;
        dst[tid] = src[tid];
        dst[tid + 1024] = src[tid + 1024];
    }
    // stage LDS-resident gate weights: row g = tid, stride 29 (bank-conflict-free)
#pragma unroll
    for (int q = 0; q < 28; ++q) W_l[tid * 29 + q] = WlB[q * 1024 + tid];
    // reg-resident gate weights (xw-part, 64 pairs)
    uint32 w_r[64];
#pragma unroll
    for (int q = 0; q < 64; ++q) w_r[q] = WrA[q * 1024 + tid];
    const float bias_r = b_ih[tid] + b_hh[tid];
    float c_r = 0.f;  // c-state (threads 0..255)
    if (tid < 128) ve_s[tid] = v_e[tid];
    if (tid < 192) vh_s[tid] = 0u;
    if (tid < 256) hsh_s[tid] = 0u;
    __syncthreads();

    for (int t = 0; t < 128; ++t) {
        // x_t prefetch for softmax (wave 0)
        float2 xv = make_float2(0.f, 0.f);
        if (tid < 64) xv = *(const float2*)(x + (b * 128 + t) * 128 + 2 * tid);

        // ---- gate GEMV, h-dependent parts (LDS-resident + streamed) ----
        float acc = bias_r;
#pragma unroll
        for (int q = 0; q < 28; ++q) acc = fdot2(W_l[tid * 29 + q], vh_s[64 + q], acc);
#pragma unroll 10
        for (int q = 0; q < 100; ++q) acc = fdot2(WsC[q * 1024 + tid], vh_s[92 + q], acc);

        // ---- ph1: web[s] partials, thread (s=lane7, ch): j-pairs [32ch, 32ch+32) ----
        {
            float a1 = 0.f;
#pragma unroll 8
            for (int q = 0; q < 32; ++q)
                a1 = fdot2(WeT[q * 1024 + tid], hsh_s[ch * 32 + q], a1);
            scr[tid] = a1;  // [ch][s]
        }
        __syncthreads();  // B1
        if (tid < 128) {
            float w = 0.f;
#pragma unroll
            for (int g = 0; g < 8; ++g) w += scr[g * 128 + tid];
            web_s[tid] = w;
        }
        __syncthreads();  // B2

        // ---- ph2: score partials, thread (n=lane7, ch): s in [16ch, 16ch+16) ----
        {
            float a2 = 0.f;
#pragma unroll 4
            for (int k = 0; k < 16; ++k) {
                int ss = ch * 16 + k;
                a2 += ve_s[ss] * fast_tanh(web_s[ss] + bfu(Ux_s[ss * 128 + lane7]));
            }
            scr[tid] = a2;  // [ch][n]
        }
        __syncthreads();  // B3

        // ---- ph3: softmax + xw publish (wave 0; lane owns n=2l, 2l+1) ----
        if (tid < 64) {
            float v0 = 0.f, v1 = 0.f;
#pragma unroll
            for (int g = 0; g < 8; ++g) {
                v0 += scr[g * 128 + 2 * tid];
                v1 += scr[g * 128 + 2 * tid + 1];
            }
            float m = fmaxf(v0, v1);
#pragma unroll
            for (int off = 32; off > 0; off >>= 1) m = fmaxf(m, __shfl_xor(m, off));
            float e0 = __expf(v0 - m), e1 = __expf(v1 - m);
            float ssum = e0 + e1;
#pragma unroll
            for (int off = 32; off > 0; off >>= 1) ssum += __shfl_xor(ssum, off);
            float inv = __fdividef(1.f, ssum);
            vh_s[tid] = pack_f16(xv.x * e0 * inv, xv.y * e1 * inv);
        }
        __syncthreads();  // B4

        // ---- gate GEMV, xw-part from registers; write gates ----
#pragma unroll
        for (int q = 0; q < 64; ++q) acc = fdot2(w_r[q], vh_s[q], acc);
        scr[tid] = acc;   // gates, [gg]
        __syncthreads();  // B5

        // ---- pointwise + publish h/c (threads 0..255, thread = h-unit j) ----
        if (tid < 256) {
            const int j = tid;
            float gi = scr[j], gf = scr[256 + j], gG = scr[512 + j], go = scr[768 + j];
            float c2 = fast_sigmoid(gf) * c_r + fast_sigmoid(gi) * fast_tanh(gG);
            float h2 = fast_sigmoid(go) * fast_tanh(c2);
            c_r = c2;
            out[(t * 128 + b) * 256 + j] = h2;
            float hn = __shfl_xor(h2, 1);
            float cn = __shfl_xor(c2, 1);
            if (!(j & 1)) {
                uint32 hp = pack_f16(h2, hn);
                vh_s[64 + (j >> 1)] = hp;
                hsh_s[j >> 1] = hp;
                hsh_s[128 + (j >> 1)] = pack_f16(c2, cn);
            }
        }
        __syncthreads();  // B6
    }
}

extern "C" void kernel_launch(void* const* d_in, const int* in_sizes, int n_in,
                              void* d_out, int out_size, void* d_ws, size_t ws_size,
                              hipStream_t stream) {
    const float* x    = (const float*)d_in[0];
    const float* We   = (const float*)d_in[1];
    const float* Ue   = (const float*)d_in[2];
    const float* v_e  = (const float*)d_in[3];
    const float* W_ih = (const float*)d_in[4];
    const float* W_hh = (const float*)d_in[5];
    const float* b_ih = (const float*)d_in[6];
    const float* b_hh = (const float*)d_in[7];
    float* out = (float*)d_out;

    char* w = (char*)d_ws;
    unsigned short* Uxg = (unsigned short*)w;   // 4 MB
    uint32* WrA = (uint32*)(w + 4194304);       // 256 KB
    uint32* WlB = (uint32*)(w + 4456448);       // 112 KB
    uint32* WsC = (uint32*)(w + 4571136);       // 400 KB
    uint32* WeT = (uint32*)(w + 4980736);       // 128 KB

    prep_weights<<<896, 256, 0, stream>>>(We, W_ih, W_hh, WrA, WlB, WsC, WeT);
    ux_kernel<<<256, 512, 0, stream>>>(x, Ue, Uxg);
    encoder_kernel<<<128, NT, 0, stream>>>(x, v_e, b_ih, b_hh, Uxg,
                                           WrA, WlB, WsC, WeT, out);
}